// Round 3
// baseline (579.710 us; speedup 1.0000x reference)
//
#include <hip/hip_runtime.h>
#include <hip/hip_fp16.h>
#include <type_traits>

#define NEG_SLOPE 0.2f
#define BKT_SHIFT 8
#define BKT_SIZE (1 << BKT_SHIFT)     // 256 dst nodes per bucket
#define BKT_CAP 12288                 // arena slots/bucket (mean 4096; overflow ~impossible)
#define P1_EPT 16                     // edges per thread in partition pass

typedef __attribute__((ext_vector_type(8))) short short8;
typedef __attribute__((ext_vector_type(4))) float float4v;

__device__ inline int rfl_i(int v) { return __builtin_amdgcn_readfirstlane(v); }

// round-to-nearest-even fp32 -> bf16
__device__ inline unsigned short f2bf(float f) {
    unsigned u = __float_as_uint(f);
    unsigned r = u + 0x7FFFu + ((u >> 16) & 1u);
    return (unsigned short)(r >> 16);
}
__device__ inline float bf2f(unsigned short b) {
    return __uint_as_float(((unsigned)b) << 16);
}

// ---------------- partition body (arena by dst>>8; gcur = pure counts) ----------------
// Record packed to 4B: src<<8 | (dst & 255)   (src < 2^17 -> 25 bits).
__device__ __forceinline__ void partition_body(
        const int* __restrict__ src, const int* __restrict__ dst, int e,
        int* __restrict__ gcur, int* __restrict__ part, int nbkt, int b_id,
        char* smem) {
    int (*cnt)[392]    = (int(*)[392])smem;
    int (*base_l)[392] = (int(*)[392])(smem + 4 * 392 * sizeof(int));
    int t = threadIdx.x;
    int wv = t >> 6;
    int cb = b_id * (256 * P1_EPT);
    for (int i = t; i < 4 * 392; i += 256) ((int*)cnt)[i] = 0;
    __syncthreads();
    int sr[P1_EPT], ds[P1_EPT], rk[P1_EPT];
#pragma unroll
    for (int i4 = 0; i4 < P1_EPT / 4; ++i4) {
        int eid0 = cb + (i4 * 256 + t) * 4;
        int4 s4, d4;
        bool full = (eid0 + 3 < e);
        if (full) {
            s4 = *(const int4*)(src + eid0);
            d4 = *(const int4*)(dst + eid0);
        }
#pragma unroll
        for (int j = 0; j < 4; ++j) {
            int i = i4 * 4 + j;
            int eid = eid0 + j;
            if (full) {
                sr[i] = (&s4.x)[j];
                ds[i] = (&d4.x)[j];
            } else if (eid < e) {
                sr[i] = src[eid];
                ds[i] = dst[eid];
            }
            rk[i] = (eid < e) ? atomicAdd(&cnt[wv][ds[i] >> BKT_SHIFT], 1) : -1;
        }
    }
    __syncthreads();
    for (int b = t; b < nbkt; b += 256) {
        int c0 = cnt[0][b], c1 = cnt[1][b], c2 = cnt[2][b], c3 = cnt[3][b];
        int tot = c0 + c1 + c2 + c3;
        if (tot > 0) {
            int gb = b * BKT_CAP + atomicAdd(&gcur[b], tot);
            base_l[0][b] = gb;
            base_l[1][b] = gb + c0;
            base_l[2][b] = gb + c0 + c1;
            base_l[3][b] = gb + c0 + c1 + c2;
        }
    }
    __syncthreads();
#pragma unroll
    for (int i = 0; i < P1_EPT; ++i) {
        if (rk[i] >= 0) {
            int b = ds[i] >> BKT_SHIFT;
            part[base_l[wv][b] + rk[i]] = (sr[i] << BKT_SHIFT) | (ds[i] & (BKT_SIZE - 1));
        }
    }
}

// ---------------- finesort (fused bbase scan) ----------------
__global__ __launch_bounds__(256) void finesort3(
        const int* __restrict__ part, const int* __restrict__ gcur,
        int* __restrict__ row_off, int* __restrict__ csr_src,
        int n, int e_total, int nbkt) {
    __shared__ int cnt[BKT_SIZE];
    __shared__ int cur[BKT_SIZE];
    __shared__ int tmp[BKT_SIZE];
    int b = blockIdx.x, t = threadIdx.x;
    // bbase = sum of gcur[0..b)  (gcur holds pure counts)
    int i1 = 256 + t;
    int v0 = (t < b) ? gcur[t] : 0;
    int v1 = (i1 < b) ? gcur[i1] : 0;
    tmp[t] = v0 + v1;
    __syncthreads();
    for (int o = 128; o > 0; o >>= 1) {
        if (t < o) tmp[t] += tmp[t + o];
        __syncthreads();
    }
    int bbase_b = tmp[0];
    __syncthreads();

    int d0 = b << BKT_SHIFT;
    int nloc = min(BKT_SIZE, n - d0);
    cnt[t] = 0;
    __syncthreads();
    int abase = b * BKT_CAP, aend = abase + gcur[b];
    for (int i = abase + t; i < aend; i += 256)
        atomicAdd(&cnt[part[i] & (BKT_SIZE - 1)], 1);
    __syncthreads();
    int c = cnt[t];
    tmp[t] = c;
    __syncthreads();
    for (int o = 1; o < 256; o <<= 1) {
        int x = tmp[t];
        int y = (t >= o) ? tmp[t - o] : 0;
        __syncthreads();
        tmp[t] = x + y;
        __syncthreads();
    }
    int pos0 = bbase_b + tmp[t] - c;
    cur[t] = pos0;
    if (t < nloc) row_off[d0 + t] = pos0;
    if (b == nbkt - 1 && t == 0) row_off[n] = e_total;
    __syncthreads();
    for (int i = abase + t; i < aend; i += 256) {
        int pk = part[i];
        int pos = atomicAdd(&cur[pk & (BKT_SIZE - 1)], 1);
        csr_src[pos] = ((unsigned)pk) >> BKT_SHIFT;
    }
}

// ---------------- MFMA GEMM body (in-kernel W decomposition) ----------------
// h_sliced[s][v][8] (s=F>>3) = x[N,K] @ W[K,64] via v_mfma_f32_16x16x32_bf16,
// bf16x3 split. IN=float row-major (layer1) or __half sliced (layer2).
template <int KT, typename IN, bool SLICED_IN>
__device__ __forceinline__ void gemm_body(
        const IN* __restrict__ x, const float* __restrict__ W,
        const float* __restrict__ al, const float* __restrict__ ar,
        __half* __restrict__ hs, float* __restrict__ el,
        float* __restrict__ er, int n, int bid, int nblocks, char* smem) {
    constexpr int K = KT * 32;
    constexpr int WFRAG = KT * 4 * 64 * 8;   // shorts
    unsigned short* Wh = (unsigned short*)smem;
    unsigned short* Wl = Wh + WFRAG;
    // decompose W (raw fp32, [K,64]) into MFMA frag order, bf16 hi/lo, in LDS
    for (int idx = threadIdx.x; idx < KT * 4 * 64; idx += 256) {
        int lane = idx & 63, fbkt = idx >> 6;
        int fb = fbkt & 3, kt = fbkt >> 2;
        int q = lane >> 4, c = lane & 15;
#pragma unroll
        for (int j = 0; j < 8; ++j) {
            float w = W[(kt * 32 + q * 8 + j) * 64 + fb * 16 + c];
            unsigned short hi = f2bf(w);
            Wh[idx * 8 + j] = hi;
            Wl[idx * 8 + j] = f2bf(w - bf2f(hi));
        }
    }
    __syncthreads();

    int lane = threadIdx.x & 63;
    int q = lane >> 4, c = lane & 15;
    int wave = bid * 4 + (int)(threadIdx.x >> 6);
    int nwaves = nblocks * 4;
    int ntiles = (n + 15) >> 4;

    float alv[4], arv[4];
#pragma unroll
    for (int fb = 0; fb < 4; ++fb) {
        alv[fb] = al[fb * 16 + c];
        arv[fb] = ar[fb * 16 + c];
    }

    for (int t = wave; t < ntiles; t += nwaves) {
        int v0 = t * 16;
        int row = min(v0 + c, n - 1);

        short8 Ah[KT], Al[KT];
#pragma unroll
        for (int kt = 0; kt < KT; ++kt) {
            float xv[8];
            if constexpr (!SLICED_IN) {
                const IN* xp = x + (size_t)row * K + kt * 32 + q * 8;
                *(float4*)&xv[0] = *(const float4*)xp;
                *(float4*)&xv[4] = *(const float4*)(xp + 4);
            } else {
                // sliced __half input: features kt*32+q*8..+8 = slice kt*4+q
                const IN* xp = x + ((size_t)(kt * 4 + q) * n + row) * 8;
                __half hh[8];
                *(uint4*)hh = *(const uint4*)xp;
#pragma unroll
                for (int j = 0; j < 8; ++j) xv[j] = __half2float(hh[j]);
            }
#pragma unroll
            for (int j = 0; j < 8; ++j) {
                unsigned short hi = f2bf(xv[j]);
                Ah[kt][j] = (short)hi;
                Al[kt][j] = (short)f2bf(xv[j] - bf2f(hi));
            }
        }

        float4v acc[4];
#pragma unroll
        for (int fb = 0; fb < 4; ++fb) acc[fb] = (float4v)0.f;

#pragma unroll
        for (int kt = 0; kt < KT; ++kt) {
#pragma unroll
            for (int fb = 0; fb < 4; ++fb) {
                short8 bh = *(const short8*)&Wh[((kt * 4 + fb) * 64 + lane) * 8];
                short8 bl = *(const short8*)&Wl[((kt * 4 + fb) * 64 + lane) * 8];
                acc[fb] = __builtin_amdgcn_mfma_f32_16x16x32_bf16(Ah[kt], bh, acc[fb], 0, 0, 0);
                acc[fb] = __builtin_amdgcn_mfma_f32_16x16x32_bf16(Al[kt], bh, acc[fb], 0, 0, 0);
                acc[fb] = __builtin_amdgcn_mfma_f32_16x16x32_bf16(Ah[kt], bl, acc[fb], 0, 0, 0);
            }
        }

#pragma unroll
        for (int r = 0; r < 4; ++r) {
            int v = v0 + q * 4 + r;
            float pl = 0.f, pr = 0.f;
            bool ok = (v < n);
#pragma unroll
            for (int fb = 0; fb < 4; ++fb) {
                float hv = acc[fb][r];
                if (ok) {
                    // sliced write: F = fb*16+c -> slice fb*2+(c>>3), sub c&7
                    size_t off = ((size_t)(fb * 2 + (c >> 3)) * n + v) * 8 + (c & 7);
                    hs[off] = __float2half(hv);
                }
                pl = fmaf(hv, alv[fb], pl);
                pr = fmaf(hv, arv[fb], pr);
            }
#pragma unroll
            for (int off = 8; off > 0; off >>= 1) {
                pl += __shfl_xor(pl, off);
                pr += __shfl_xor(pr, off);
            }
            if (ok && c == 0) { el[v] = pl; er[v] = pr; }
        }
    }
}

// fused: blocks [0,npb) = partition, [npb, grid) = gemm layer1.
// Disjoint memory: partition writes arena(d_out)+gcur; gemm writes hs/el/er.
__global__ __launch_bounds__(256) void part_gemm1(
        const int* __restrict__ src, const int* __restrict__ dst, int e,
        int* __restrict__ gcur, int* __restrict__ part, int nbkt, int npb,
        const float* __restrict__ x, const float* __restrict__ W1,
        const float* __restrict__ al, const float* __restrict__ ar,
        __half* __restrict__ hs, float* __restrict__ el,
        float* __restrict__ er, int n) {
    __shared__ char smem[32768];   // max(partition 12.5KB, gemm KT=4 32KB)
    int b = (int)blockIdx.x;
    if (b < npb)
        partition_body(src, dst, e, gcur, part, nbkt, b, smem);
    else
        gemm_body<4, float, false>(x, W1, al, ar, hs, el, er, n, b - npb,
                                   (int)gridDim.x - npb, smem);
}

template <int KT, typename IN, bool SLICED_IN>
__global__ __launch_bounds__(256) void gemm_mfma_kernel(
        const IN* __restrict__ x, const float* __restrict__ W,
        const float* __restrict__ al, const float* __restrict__ ar,
        __half* __restrict__ hs, float* __restrict__ el,
        float* __restrict__ er, int n) {
    __shared__ char smem[KT * 4 * 64 * 8 * 2 * 2];
    gemm_body<KT, IN, SLICED_IN>(x, W, al, ar, hs, el, er, n, (int)blockIdx.x,
                                 (int)gridDim.x, smem);
}

// ---------------- XCD-sliced softmax-aggregate ----------------
// blockIdx&7 selects the feature slice (8 of 64 feats); with round-robin
// block->XCD dispatch, slice s lands on XCD s, whose 1.6MB h-slice table
// (+0.4MB el) is L2-resident -> gathers become L2 hits instead of 128B HBM/L3
// misses. Softmax (el gather + expf + sum) is recomputed per slice (cheap).
// Each wave: two nodes (32-lane groups); each lane owns one edge:
// 16B h gather + 8 FMA, no in-loop shuffles.
// OUT=__half: sliced layout (feeds gemm2). OUT=float: row-major d_out.
template <typename OUT>
__global__ __launch_bounds__(256) void agg_sliced(
        const int* __restrict__ row_off, const int* __restrict__ csr_src,
        const __half* __restrict__ hs, const float* __restrict__ el,
        const float* __restrict__ er, const float* __restrict__ bias,
        OUT* __restrict__ out, int n, int do_relu) {
    int lane = threadIdx.x & 63;
    int g = lane >> 5;        // node sub-group within wave
    int l = lane & 31;        // edge slot within group
    int slice = blockIdx.x & 7;
    int wave = ((int)blockIdx.x >> 3) * 4 + (int)(threadIdx.x >> 6);
    int nwps = ((int)gridDim.x >> 3) * 4;     // waves per slice
    const __half* __restrict__ hsl = hs + (size_t)slice * n * 8;

    float bf[8];
    *(float4*)&bf[0] = ((const float4*)bias)[slice * 2];
    *(float4*)&bf[4] = ((const float4*)bias)[slice * 2 + 1];

    for (int v0 = wave * 2; v0 < n; v0 += nwps * 2) {
        int v = v0 + g;
        bool act = (v < n);
        int vc = act ? v : (n - 1);
        int rs = row_off[vc];
        int re = act ? row_off[vc + 1] : rs;
        float er_v = er[vc];

        float acc[8];
#pragma unroll
        for (int f = 0; f < 8; ++f) acc[f] = 0.f;
        float ssum = 0.f;

        for (int base = rs; base < re; base += 32) {
            int idx = base + l;
            bool on = (idx < re);
            int s_e = on ? csr_src[idx] : 0;
            uint4 hv = make_uint4(0, 0, 0, 0);
            float ex = 0.f;
            if (on) {
                hv = *(const uint4*)(hsl + (size_t)s_e * 8);
                float ev = el[s_e] + er_v;
                ev = (ev >= 0.f) ? ev : NEG_SLOPE * ev;
                ex = __expf(ev);
            }
            ssum += ex;
            __half2* hp = (__half2*)&hv;
#pragma unroll
            for (int f2 = 0; f2 < 4; ++f2) {
                float2 ff = __half22float2(hp[f2]);
                acc[2 * f2]     = fmaf(ex, ff.x, acc[2 * f2]);
                acc[2 * f2 + 1] = fmaf(ex, ff.y, acc[2 * f2 + 1]);
            }
        }

        // reduce across the 32-lane group
#pragma unroll
        for (int off = 16; off >= 1; off >>= 1) {
            ssum += __shfl_xor(ssum, off);
#pragma unroll
            for (int f = 0; f < 8; ++f) acc[f] += __shfl_xor(acc[f], off);
        }

        if (act && l == 0) {
            bool has = (re > rs);
            float inv = has ? 1.0f / ssum : 0.f;
            float o[8];
#pragma unroll
            for (int f = 0; f < 8; ++f) {
                o[f] = has ? fmaf(acc[f], inv, bf[f]) : bf[f];
                if (do_relu) o[f] = fmaxf(o[f], 0.f);
            }
            if constexpr (std::is_same<OUT, __half>::value) {
                uint4 pk;
                __half2* pp = (__half2*)&pk;
#pragma unroll
                for (int f2 = 0; f2 < 4; ++f2)
                    pp[f2] = __float22half2_rn(make_float2(o[2 * f2], o[2 * f2 + 1]));
                *(uint4*)(out + ((size_t)slice * n + v) * 8) = pk;
            } else {
                float4* op = (float4*)(out + (size_t)v * 64 + slice * 8);
                op[0] = make_float4(o[0], o[1], o[2], o[3]);
                op[1] = make_float4(o[4], o[5], o[6], o[7]);
            }
        }
    }
}

extern "C" void kernel_launch(void* const* d_in, const int* in_sizes, int n_in,
                              void* d_out, int out_size, void* d_ws, size_t ws_size,
                              hipStream_t stream) {
    (void)n_in; (void)out_size; (void)ws_size;
    const float* features = (const float*)d_in[0];
    // d_in[1] = edge_weights, unused by the reference forward
    const int*   src = (const int*)d_in[2];
    const int*   dst = (const int*)d_in[3];
    const float* W1  = (const float*)d_in[4];
    const float* al1 = (const float*)d_in[5];
    const float* ar1 = (const float*)d_in[6];
    const float* b1  = (const float*)d_in[7];
    const float* W2  = (const float*)d_in[8];
    const float* al2 = (const float*)d_in[9];
    const float* ar2 = (const float*)d_in[10];
    const float* b2  = (const float*)d_in[11];

    const int n = in_sizes[0] / 128;   // 100000
    const int e = in_sizes[2];         // 1600000
    float* out = (float*)d_out;

    char* p = (char*)d_ws;
    auto alloc = [&](size_t bytes) -> char* {
        char* q = p;
        p += (bytes + 255) & ~(size_t)255;
        return q;
    };
    int*    row_off = (int*)alloc((size_t)(n + 1) * 4);
    int*    csr_src = (int*)alloc((size_t)e * 4);
    __half* h16     = (__half*)alloc((size_t)n * 64 * 2);   // sliced [8][n][8]
    __half* hr      = (__half*)alloc((size_t)n * 64 * 2);   // sliced [8][n][8]
    float*  el      = (float*)alloc((size_t)n * 4);
    float*  er      = (float*)alloc((size_t)n * 4);
    int*    gcur    = (int*)alloc(512 * 4);
    // arena (nbkt*CAP ints = 19.2MB) lives in d_out (25.6MB): only written by
    // agg2 at the very end; partition/finesort consume it long before.
    int*    part    = (int*)d_out;

    const int nbkt = (n + BKT_SIZE - 1) >> BKT_SHIFT;            // 391
    const int npb  = (e + 256 * P1_EPT - 1) / (256 * P1_EPT);    // 391

    hipMemsetAsync(gcur, 0, 512 * sizeof(int), stream);

    // partition (CSR coarse pass) runs concurrently with gemm1 (independent)
    part_gemm1<<<npb + 512, 256, 0, stream>>>(src, dst, e, gcur, part, nbkt, npb,
                                              features, W1, al1, ar1, h16, el, er, n);
    // fine sort (includes its own bbase scan)
    finesort3<<<nbkt, 256, 0, stream>>>(part, gcur, row_off, csr_src, n, e, nbkt);

    // layer 1 aggregate (sliced): hr in sliced half layout
    agg_sliced<__half><<<2048, 256, 0, stream>>>(row_off, csr_src, h16, el, er, b1, hr, n, 1);

    // layer 2
    gemm_mfma_kernel<2, __half, true><<<512, 256, 0, stream>>>(hr, W2, al2, ar2,
                                                               h16, el, er, n);
    agg_sliced<float><<<2048, 256, 0, stream>>>(row_off, csr_src, h16, el, er, b2, out, n, 0);
}

// Round 4
// 320.531 us; speedup vs baseline: 1.8086x; 1.8086x over previous
//
#include <hip/hip_runtime.h>
#include <hip/hip_fp16.h>
#include <type_traits>

#define NEG_SLOPE 0.2f
#define BKT_SHIFT 8
#define BKT_SIZE (1 << BKT_SHIFT)     // 256 dst nodes per bucket
#define BKT_CAP 12288                 // arena slots/bucket (mean 4096; overflow ~impossible)
#define P1_EPT 16                     // edges per thread in partition pass

typedef __attribute__((ext_vector_type(8))) short short8;
typedef __attribute__((ext_vector_type(4))) float float4v;

__device__ inline int rfl_i(int v) { return __builtin_amdgcn_readfirstlane(v); }

// round-to-nearest-even fp32 -> bf16
__device__ inline unsigned short f2bf(float f) {
    unsigned u = __float_as_uint(f);
    unsigned r = u + 0x7FFFu + ((u >> 16) & 1u);
    return (unsigned short)(r >> 16);
}
__device__ inline float bf2f(unsigned short b) {
    return __uint_as_float(((unsigned)b) << 16);
}

// ---------------- partition body (arena by dst>>8; gcur = pure counts) ----------------
// Record packed to 4B: src<<8 | (dst & 255)   (src < 2^17 -> 25 bits).
__device__ __forceinline__ void partition_body(
        const int* __restrict__ src, const int* __restrict__ dst, int e,
        int* __restrict__ gcur, int* __restrict__ part, int nbkt, int b_id,
        char* smem) {
    int (*cnt)[392]    = (int(*)[392])smem;
    int (*base_l)[392] = (int(*)[392])(smem + 4 * 392 * sizeof(int));
    int t = threadIdx.x;
    int wv = t >> 6;
    int cb = b_id * (256 * P1_EPT);
    for (int i = t; i < 4 * 392; i += 256) ((int*)cnt)[i] = 0;
    __syncthreads();
    int sr[P1_EPT], ds[P1_EPT], rk[P1_EPT];
#pragma unroll
    for (int i4 = 0; i4 < P1_EPT / 4; ++i4) {
        int eid0 = cb + (i4 * 256 + t) * 4;
        int4 s4, d4;
        bool full = (eid0 + 3 < e);
        if (full) {
            s4 = *(const int4*)(src + eid0);
            d4 = *(const int4*)(dst + eid0);
        }
#pragma unroll
        for (int j = 0; j < 4; ++j) {
            int i = i4 * 4 + j;
            int eid = eid0 + j;
            if (full) {
                sr[i] = (&s4.x)[j];
                ds[i] = (&d4.x)[j];
            } else if (eid < e) {
                sr[i] = src[eid];
                ds[i] = dst[eid];
            }
            rk[i] = (eid < e) ? atomicAdd(&cnt[wv][ds[i] >> BKT_SHIFT], 1) : -1;
        }
    }
    __syncthreads();
    for (int b = t; b < nbkt; b += 256) {
        int c0 = cnt[0][b], c1 = cnt[1][b], c2 = cnt[2][b], c3 = cnt[3][b];
        int tot = c0 + c1 + c2 + c3;
        if (tot > 0) {
            int gb = b * BKT_CAP + atomicAdd(&gcur[b], tot);
            base_l[0][b] = gb;
            base_l[1][b] = gb + c0;
            base_l[2][b] = gb + c0 + c1;
            base_l[3][b] = gb + c0 + c1 + c2;
        }
    }
    __syncthreads();
#pragma unroll
    for (int i = 0; i < P1_EPT; ++i) {
        if (rk[i] >= 0) {
            int b = ds[i] >> BKT_SHIFT;
            part[base_l[wv][b] + rk[i]] = (sr[i] << BKT_SHIFT) | (ds[i] & (BKT_SIZE - 1));
        }
    }
}

// ---------------- finesort (fused bbase scan) ----------------
__global__ __launch_bounds__(256) void finesort3(
        const int* __restrict__ part, const int* __restrict__ gcur,
        int* __restrict__ row_off, int* __restrict__ csr_src,
        int n, int e_total, int nbkt) {
    __shared__ int cnt[BKT_SIZE];
    __shared__ int cur[BKT_SIZE];
    __shared__ int tmp[BKT_SIZE];
    int b = blockIdx.x, t = threadIdx.x;
    // bbase = sum of gcur[0..b)  (gcur holds pure counts)
    int i1 = 256 + t;
    int v0 = (t < b) ? gcur[t] : 0;
    int v1 = (i1 < b) ? gcur[i1] : 0;
    tmp[t] = v0 + v1;
    __syncthreads();
    for (int o = 128; o > 0; o >>= 1) {
        if (t < o) tmp[t] += tmp[t + o];
        __syncthreads();
    }
    int bbase_b = tmp[0];
    __syncthreads();

    int d0 = b << BKT_SHIFT;
    int nloc = min(BKT_SIZE, n - d0);
    cnt[t] = 0;
    __syncthreads();
    int abase = b * BKT_CAP, aend = abase + gcur[b];
    for (int i = abase + t; i < aend; i += 256)
        atomicAdd(&cnt[part[i] & (BKT_SIZE - 1)], 1);
    __syncthreads();
    int c = cnt[t];
    tmp[t] = c;
    __syncthreads();
    for (int o = 1; o < 256; o <<= 1) {
        int x = tmp[t];
        int y = (t >= o) ? tmp[t - o] : 0;
        __syncthreads();
        tmp[t] = x + y;
        __syncthreads();
    }
    int pos0 = bbase_b + tmp[t] - c;
    cur[t] = pos0;
    if (t < nloc) row_off[d0 + t] = pos0;
    if (b == nbkt - 1 && t == 0) row_off[n] = e_total;
    __syncthreads();
    for (int i = abase + t; i < aend; i += 256) {
        int pk = part[i];
        int pos = atomicAdd(&cur[pk & (BKT_SIZE - 1)], 1);
        csr_src[pos] = ((unsigned)pk) >> BKT_SHIFT;
    }
}

// ---------------- MFMA GEMM body (in-kernel W decomposition) ----------------
// h_sliced16[s][v][16] (s=F>>4) = x[N,K] @ W[K,64] via mfma_f32_16x16x32_bf16,
// bf16x3 split. IN=float row-major (layer1) or __half sliced16 (layer2).
template <int KT, typename IN, bool SLICED_IN>
__device__ __forceinline__ void gemm_body(
        const IN* __restrict__ x, const float* __restrict__ W,
        const float* __restrict__ al, const float* __restrict__ ar,
        __half* __restrict__ hs, float* __restrict__ el,
        float* __restrict__ er, int n, int bid, int nblocks, char* smem) {
    constexpr int K = KT * 32;
    constexpr int WFRAG = KT * 4 * 64 * 8;   // shorts
    unsigned short* Wh = (unsigned short*)smem;
    unsigned short* Wl = Wh + WFRAG;
    // decompose W (raw fp32, [K,64]) into MFMA frag order, bf16 hi/lo, in LDS
    for (int idx = threadIdx.x; idx < KT * 4 * 64; idx += 256) {
        int lane = idx & 63, fbkt = idx >> 6;
        int fb = fbkt & 3, kt = fbkt >> 2;
        int q = lane >> 4, c = lane & 15;
#pragma unroll
        for (int j = 0; j < 8; ++j) {
            float w = W[(kt * 32 + q * 8 + j) * 64 + fb * 16 + c];
            unsigned short hi = f2bf(w);
            Wh[idx * 8 + j] = hi;
            Wl[idx * 8 + j] = f2bf(w - bf2f(hi));
        }
    }
    __syncthreads();

    int lane = threadIdx.x & 63;
    int q = lane >> 4, c = lane & 15;
    int wave = bid * 4 + (int)(threadIdx.x >> 6);
    int nwaves = nblocks * 4;
    int ntiles = (n + 15) >> 4;

    float alv[4], arv[4];
#pragma unroll
    for (int fb = 0; fb < 4; ++fb) {
        alv[fb] = al[fb * 16 + c];
        arv[fb] = ar[fb * 16 + c];
    }

    for (int t = wave; t < ntiles; t += nwaves) {
        int v0 = t * 16;
        int row = min(v0 + c, n - 1);

        short8 Ah[KT], Al[KT];
#pragma unroll
        for (int kt = 0; kt < KT; ++kt) {
            float xv[8];
            if constexpr (!SLICED_IN) {
                const IN* xp = x + (size_t)row * K + kt * 32 + q * 8;
                *(float4*)&xv[0] = *(const float4*)xp;
                *(float4*)&xv[4] = *(const float4*)(xp + 4);
            } else {
                // sliced16 __half input: feats kt*32+q*8..+8 ->
                // slice 2*kt + (q>>1), sub (q&1)*8
                const IN* xp = x + ((size_t)(2 * kt + (q >> 1)) * n + row) * 16 + (q & 1) * 8;
                __half hh[8];
                *(uint4*)hh = *(const uint4*)xp;
#pragma unroll
                for (int j = 0; j < 8; ++j) xv[j] = __half2float(hh[j]);
            }
#pragma unroll
            for (int j = 0; j < 8; ++j) {
                unsigned short hi = f2bf(xv[j]);
                Ah[kt][j] = (short)hi;
                Al[kt][j] = (short)f2bf(xv[j] - bf2f(hi));
            }
        }

        float4v acc[4];
#pragma unroll
        for (int fb = 0; fb < 4; ++fb) acc[fb] = (float4v)0.f;

#pragma unroll
        for (int kt = 0; kt < KT; ++kt) {
#pragma unroll
            for (int fb = 0; fb < 4; ++fb) {
                short8 bh = *(const short8*)&Wh[((kt * 4 + fb) * 64 + lane) * 8];
                short8 bl = *(const short8*)&Wl[((kt * 4 + fb) * 64 + lane) * 8];
                acc[fb] = __builtin_amdgcn_mfma_f32_16x16x32_bf16(Ah[kt], bh, acc[fb], 0, 0, 0);
                acc[fb] = __builtin_amdgcn_mfma_f32_16x16x32_bf16(Al[kt], bh, acc[fb], 0, 0, 0);
                acc[fb] = __builtin_amdgcn_mfma_f32_16x16x32_bf16(Ah[kt], bl, acc[fb], 0, 0, 0);
            }
        }

#pragma unroll
        for (int r = 0; r < 4; ++r) {
            int v = v0 + q * 4 + r;
            float pl = 0.f, pr = 0.f;
            bool ok = (v < n);
#pragma unroll
            for (int fb = 0; fb < 4; ++fb) {
                float hv = acc[fb][r];
                if (ok) {
                    // sliced16 write: F = fb*16+c -> slice fb, sub c
                    hs[((size_t)fb * n + v) * 16 + c] = __float2half(hv);
                }
                pl = fmaf(hv, alv[fb], pl);
                pr = fmaf(hv, arv[fb], pr);
            }
#pragma unroll
            for (int off = 8; off > 0; off >>= 1) {
                pl += __shfl_xor(pl, off);
                pr += __shfl_xor(pr, off);
            }
            if (ok && c == 0) { el[v] = pl; er[v] = pr; }
        }
    }
}

// fused: blocks [0,npb) = partition, [npb, grid) = gemm layer1.
__global__ __launch_bounds__(256) void part_gemm1(
        const int* __restrict__ src, const int* __restrict__ dst, int e,
        int* __restrict__ gcur, int* __restrict__ part, int nbkt, int npb,
        const float* __restrict__ x, const float* __restrict__ W1,
        const float* __restrict__ al, const float* __restrict__ ar,
        __half* __restrict__ hs, float* __restrict__ el,
        float* __restrict__ er, int n) {
    __shared__ char smem[32768];   // max(partition 12.5KB, gemm KT=4 32KB)
    int b = (int)blockIdx.x;
    if (b < npb)
        partition_body(src, dst, e, gcur, part, nbkt, b, smem);
    else
        gemm_body<4, float, false>(x, W1, al, ar, hs, el, er, n, b - npb,
                                   (int)gridDim.x - npb, smem);
}

template <int KT, typename IN, bool SLICED_IN>
__global__ __launch_bounds__(256) void gemm_mfma_kernel(
        const IN* __restrict__ x, const float* __restrict__ W,
        const float* __restrict__ al, const float* __restrict__ ar,
        __half* __restrict__ hs, float* __restrict__ el,
        float* __restrict__ er, int n) {
    __shared__ char smem[KT * 4 * 64 * 8 * 2 * 2];
    gemm_body<KT, IN, SLICED_IN>(x, W, al, ar, hs, el, er, n, (int)blockIdx.x,
                                 (int)gridDim.x, smem);
}

// ---------------- edge-weight precompute (per layer, once) ----------------
// ex[i] = exp(leaky(el[csr_src[i]] + er[dst(i)])) in CSR order; sden[v] = sum.
// 2 nodes per wave (32-lane groups); csr/ex accesses coalesced; el gather is
// a 0.4MB table -> L2-hit on every XCD.
__global__ __launch_bounds__(256) void edgew_kernel(
        const int* __restrict__ row_off, const int* __restrict__ csr_src,
        const float* __restrict__ el, const float* __restrict__ er,
        float* __restrict__ ex, float* __restrict__ sden, int n) {
    int lane = threadIdx.x & 63;
    int g = lane >> 5, l = lane & 31;
    int wave = ((int)blockIdx.x) * 4 + (int)(threadIdx.x >> 6);
    int nwaves = ((int)gridDim.x) * 4;
    for (int v0 = wave * 2; v0 < n; v0 += nwaves * 2) {
        int v = v0 + g;
        bool act = (v < n);
        int vc = act ? v : (n - 1);
        int rs = row_off[vc];
        int re = act ? row_off[vc + 1] : rs;
        float er_v = er[vc];
        float ssum = 0.f;
        for (int base = rs; base < re; base += 32) {
            int idx = base + l;
            bool on = (idx < re);
            float exv = 0.f;
            if (on) {
                int s_e = csr_src[idx];
                float ev = el[s_e] + er_v;
                ev = (ev >= 0.f) ? ev : NEG_SLOPE * ev;
                exv = __expf(ev);
                ex[idx] = exv;
            }
            ssum += exv;
        }
#pragma unroll
        for (int off = 16; off >= 1; off >>= 1) ssum += __shfl_xor(ssum, off);
        if (act && l == 0) sden[v] = ssum;
    }
}

// ---------------- XCD-sliced aggregate (4 slices x 16 feats) ----------------
// slice = blockIdx&3 -> XCDs {s, s+4} (round-robin dispatch): per-XCD gather
// table = 3.2MB h-slice -> L2-resident. No softmax work in-loop (ex/sden
// precomputed). 2 nodes/wave; per node 4 edge-groups x 8 lanes; lane holds
// 2 features (uint gather); inner step = 8 edges in flight.
// OUT=__half: sliced16 layout (feeds gemm2). OUT=float: row-major d_out.
template <typename OUT>
__global__ __launch_bounds__(256) void agg_s4(
        const int* __restrict__ row_off, const int* __restrict__ csr_src,
        const __half* __restrict__ hs, const float* __restrict__ ex,
        const float* __restrict__ sden, const float* __restrict__ bias,
        OUT* __restrict__ out, int n, int do_relu) {
    int lane = threadIdx.x & 63;
    int g = lane >> 5;        // node sub-group
    int l = lane & 31;
    int grp = l >> 3;         // 0..3 edge slot
    int c = l & 7;            // feature pair: feats 2c, 2c+1 of the slice
    int slice = (int)blockIdx.x & 3;
    int wave = ((int)blockIdx.x >> 2) * 4 + (int)(threadIdx.x >> 6);
    int nwps = ((int)gridDim.x >> 2) * 4;   // waves per slice
    const __half* __restrict__ hsl = hs + (size_t)slice * n * 16;

    float2 b2 = ((const float2*)(bias + slice * 16))[c];

    for (int v0 = wave * 2; v0 < n; v0 += nwps * 2) {
        int v = v0 + g;
        bool act = (v < n);
        int vc = act ? v : (n - 1);
        int rs = row_off[vc];
        int re = act ? row_off[vc + 1] : rs;
        float sv = sden[vc];

        float a0 = 0.f, a1 = 0.f;
        for (int base = rs; base < re; base += 32) {
            int idx = base + l;
            bool on = (idx < re);
            int s_e = on ? csr_src[idx] : 0;
            float exv = on ? ex[idx] : 0.f;
            int cnt = re - base;
            if (cnt > 32) cnt = 32;
            for (int j = 0; j < cnt; j += 8) {
                int i0 = (g << 5) + j + grp;
                int i1 = (g << 5) + j + 4 + grp;
                int s0 = __shfl(s_e, i0);
                int s1 = __shfl(s_e, i1);
                float e0 = __shfl(exv, i0);
                float e1 = __shfl(exv, i1);
                // both gathers issued before either consumed
                unsigned u0 = ((const unsigned*)(hsl + (size_t)s0 * 16))[c];
                unsigned u1 = ((const unsigned*)(hsl + (size_t)s1 * 16))[c];
                float2 f0 = __half22float2(*(__half2*)&u0);
                float2 f1 = __half22float2(*(__half2*)&u1);
                a0 = fmaf(e0, f0.x, a0);
                a1 = fmaf(e0, f0.y, a1);
                a0 = fmaf(e1, f1.x, a0);
                a1 = fmaf(e1, f1.y, a1);
            }
        }
        // reduce across the 4 edge-groups (lane bits 3,4)
        a0 += __shfl_xor(a0, 8);
        a1 += __shfl_xor(a1, 8);
        a0 += __shfl_xor(a0, 16);
        a1 += __shfl_xor(a1, 16);

        if (act && l < 8) {
            bool has = (re > rs);
            float inv = has ? 1.0f / sv : 0.f;
            float o0 = has ? fmaf(a0, inv, b2.x) : b2.x;
            float o1 = has ? fmaf(a1, inv, b2.y) : b2.y;
            if (do_relu) {
                o0 = fmaxf(o0, 0.f);
                o1 = fmaxf(o1, 0.f);
            }
            if constexpr (std::is_same<OUT, __half>::value) {
                __half2 pk = __float22half2_rn(make_float2(o0, o1));
                *(__half2*)(out + ((size_t)slice * n + v) * 16 + 2 * c) = pk;
            } else {
                *(float2*)(out + (size_t)v * 64 + slice * 16 + 2 * c) =
                    make_float2(o0, o1);
            }
        }
    }
}

extern "C" void kernel_launch(void* const* d_in, const int* in_sizes, int n_in,
                              void* d_out, int out_size, void* d_ws, size_t ws_size,
                              hipStream_t stream) {
    (void)n_in; (void)out_size; (void)ws_size;
    const float* features = (const float*)d_in[0];
    // d_in[1] = edge_weights, unused by the reference forward
    const int*   src = (const int*)d_in[2];
    const int*   dst = (const int*)d_in[3];
    const float* W1  = (const float*)d_in[4];
    const float* al1 = (const float*)d_in[5];
    const float* ar1 = (const float*)d_in[6];
    const float* b1  = (const float*)d_in[7];
    const float* W2  = (const float*)d_in[8];
    const float* al2 = (const float*)d_in[9];
    const float* ar2 = (const float*)d_in[10];
    const float* b2  = (const float*)d_in[11];

    const int n = in_sizes[0] / 128;   // 100000
    const int e = in_sizes[2];         // 1600000
    float* out = (float*)d_out;

    char* p = (char*)d_ws;
    auto alloc = [&](size_t bytes) -> char* {
        char* q = p;
        p += (bytes + 255) & ~(size_t)255;
        return q;
    };
    int*    row_off = (int*)alloc((size_t)(n + 1) * 4);
    int*    csr_src = (int*)alloc((size_t)e * 4);
    __half* h16     = (__half*)alloc((size_t)n * 64 * 2);   // sliced16 [4][n][16]
    __half* hr      = (__half*)alloc((size_t)n * 64 * 2);   // sliced16 [4][n][16]
    float*  el      = (float*)alloc((size_t)n * 4);
    float*  er      = (float*)alloc((size_t)n * 4);
    int*    gcur    = (int*)alloc(512 * 4);
    // arena (19.2MB) lives in d_out (25.6MB): dead after finesort3.
    int*    part    = (int*)d_out;
    // layer-1 edge weights alias the (dead) arena in d_out; agg1 doesn't
    // touch d_out otherwise.
    float*  ex1     = (float*)d_out;                       // e*4 = 6.4MB
    float*  s1      = (float*)((char*)d_out + (size_t)e * 4);   // n*4
    // layer-2 edge weights alias hr (dead after gemm2 consumes it).
    float*  ex2     = (float*)hr;
    float*  s2      = (float*)((char*)hr + (size_t)e * 4);

    const int nbkt = (n + BKT_SIZE - 1) >> BKT_SHIFT;            // 391
    const int npb  = (e + 256 * P1_EPT - 1) / (256 * P1_EPT);    // 391

    hipMemsetAsync(gcur, 0, 512 * sizeof(int), stream);

    // partition (arena in d_out) runs concurrently with gemm1
    part_gemm1<<<npb + 512, 256, 0, stream>>>(src, dst, e, gcur, part, nbkt, npb,
                                              features, W1, al1, ar1, h16, el, er, n);
    finesort3<<<nbkt, 256, 0, stream>>>(part, gcur, row_off, csr_src, n, e, nbkt);

    // layer 1: edge weights once, then sliced aggregate
    edgew_kernel<<<2048, 256, 0, stream>>>(row_off, csr_src, el, er, ex1, s1, n);
    agg_s4<__half><<<2048, 256, 0, stream>>>(row_off, csr_src, h16, ex1, s1, b1, hr, n, 1);

    // layer 2
    gemm_mfma_kernel<2, __half, true><<<512, 256, 0, stream>>>(hr, W2, al2, ar2,
                                                               h16, el, er, n);
    edgew_kernel<<<2048, 256, 0, stream>>>(row_off, csr_src, el, er, ex2, s2, n);
    agg_s4<float><<<2048, 256, 0, stream>>>(row_off, csr_src, h16, ex2, s2, b2, out, n, 0);
}